// Round 1
// baseline (490.632 us; speedup 1.0000x reference)
//
#include <hip/hip_runtime.h>

typedef _Float16 f16;
typedef _Float16 f16x8 __attribute__((ext_vector_type(8)));
typedef float f32x4 __attribute__((ext_vector_type(4)));

__device__ __forceinline__ void gload_lds16(const void* g, void* l) {
  __builtin_amdgcn_global_load_lds((const __attribute__((address_space(1))) void*)g,
                                   (__attribute__((address_space(3))) void*)l, 16, 0, 0);
}

__device__ __forceinline__ f32x4 mfma16(f16x8 a, f16x8 b, f32x4 c) {
  return __builtin_amdgcn_mfma_f32_16x16x32_f16(a, b, c, 0, 0, 0);
}

// fp32 -> f16 vectorized convert (8 elems/thread)
__global__ void k_cvt(const float* __restrict__ src, f16* __restrict__ dst, int n8) {
  int i = blockIdx.x * 256 + threadIdx.x;
  if (i >= n8) return;
  const float4* s4 = reinterpret_cast<const float4*>(src) + (size_t)i * 2;
  float4 a = s4[0], b = s4[1];
  f16x8 v;
  v[0] = (f16)a.x; v[1] = (f16)a.y; v[2] = (f16)a.z; v[3] = (f16)a.w;
  v[4] = (f16)b.x; v[5] = (f16)b.y; v[6] = (f16)b.z; v[7] = (f16)b.w;
  *reinterpret_cast<f16x8*>(dst + (size_t)i * 8) = v;
}

// lora_A [256,4096] fp32 -> at [4096,256] f16 (transpose via LDS tile)
__global__ void k_cvt_at(const float* __restrict__ A, f16* __restrict__ at) {
  __shared__ float t[64][65];
  int bi = blockIdx.x, br = blockIdx.y;
  int tx = threadIdx.x & 63, ty = threadIdx.x >> 6;
#pragma unroll
  for (int p = 0; p < 16; ++p) {
    int r = p * 4 + ty;
    t[r][tx] = A[(size_t)(br * 64 + r) * 4096 + bi * 64 + tx];
  }
  __syncthreads();
#pragma unroll
  for (int p = 0; p < 16; ++p) {
    int i = p * 4 + ty;
    at[(size_t)(bi * 64 + i) * 256 + br * 64 + tx] = (f16)t[tx][i];
  }
}

// stage a 128x64 f16 tile (row0..row0+127, k0..k0+63) into LDS via global_load_lds
__device__ __forceinline__ void stage_tile(const f16* __restrict__ g, size_t row0, int k0,
                                           int ldg, f16* s, int wid, int lane) {
#pragma unroll
  for (int t = 0; t < 4; ++t) {
    int c = (wid * 4 + t) * 64 + lane;                 // chunk id 0..1023
    const f16* gp = g + (row0 + (size_t)(c >> 3)) * (size_t)ldg + k0 + (c & 7) * 8;
    gload_lds16(gp, s + (wid * 4 + t) * 512);          // wave-uniform LDS base
  }
}

// combined = base + 0.5*(lora_B @ lora_A); write f16 combined + per-row sumsq partials
__global__ __launch_bounds__(256) void k_lora(const f16* __restrict__ bh,
                                              const f16* __restrict__ at,
                                              const float* __restrict__ base,
                                              f16* __restrict__ ch,
                                              float* __restrict__ partial) {
  __shared__ f16 sA[128 * 64];
  __shared__ f16 sB[128 * 64];
  __shared__ float ssum[2][128];
  int tid = threadIdx.x;
  int wid = tid >> 6, lane = tid & 63;
  int wm = wid >> 1, wn = wid & 1;
  int ln = lane & 15, q = lane >> 4;
  int bm = blockIdx.x >> 5, bn = blockIdx.x & 31;
  int brow = bm * 128, bcol = bn * 128;
  f32x4 acc[4][4] = {};
  for (int kt = 0; kt < 256; kt += 64) {
    __syncthreads();
    stage_tile(bh, brow, kt, 256, sA, wid, lane);
    stage_tile(at, bcol, kt, 256, sB, wid, lane);
    __syncthreads();
#pragma unroll
    for (int ks = 0; ks < 2; ++ks) {
      f16x8 af[4], bf[4];
#pragma unroll
      for (int mi = 0; mi < 4; ++mi)
        af[mi] = *reinterpret_cast<const f16x8*>(&sA[(wm * 64 + mi * 16 + ln) * 64 + ks * 32 + q * 8]);
#pragma unroll
      for (int ni = 0; ni < 4; ++ni)
        bf[ni] = *reinterpret_cast<const f16x8*>(&sB[(wn * 64 + ni * 16 + ln) * 64 + ks * 32 + q * 8]);
#pragma unroll
      for (int mi = 0; mi < 4; ++mi)
#pragma unroll
        for (int ni = 0; ni < 4; ++ni)
          acc[mi][ni] = mfma16(af[mi], bf[ni], acc[mi][ni]);
    }
  }
  // epilogue: add base, write f16 combined, reduce sum-of-squares per row
#pragma unroll
  for (int mi = 0; mi < 4; ++mi) {
#pragma unroll
    for (int j = 0; j < 4; ++j) {
      int row = brow + wm * 64 + mi * 16 + q * 4 + j;
      float s = 0.f;
#pragma unroll
      for (int ni = 0; ni < 4; ++ni) {
        int col = bcol + wn * 64 + ni * 16 + ln;
        float v = base[(size_t)row * 4096 + col] + 0.5f * acc[mi][ni][j];
        ch[(size_t)row * 4096 + col] = (f16)v;
        s += v * v;
      }
#pragma unroll
      for (int m = 1; m < 16; m <<= 1) s += __shfl_xor(s, m, 64);
      if (ln == 0) ssum[wn][wm * 64 + mi * 16 + q * 4 + j] = s;
    }
  }
  __syncthreads();
  if (tid < 128) {
    float p = ssum[0][tid] + ssum[1][tid];
    partial[(size_t)(brow + tid) * 32 + bn] = p;
  }
}

// scale[o] = mag[o]*turk[o] / (||combined_o|| + eps)
__global__ void k_scale(const float* __restrict__ partial, const float* __restrict__ mag,
                        const float* __restrict__ turk, float* __restrict__ scale) {
  int o = blockIdx.x * 256 + threadIdx.x;
  float s = 0.f;
#pragma unroll
  for (int c = 0; c < 32; ++c) s += partial[(size_t)o * 32 + c];
  scale[o] = mag[o] * turk[o] / (sqrtf(s) + 1e-8f);
}

// out[m,o] = scale[o] * sum_k x[m,k]*combined[o,k] + bias[o]
__global__ __launch_bounds__(256) void k_main(const f16* __restrict__ xh,
                                              const f16* __restrict__ ch,
                                              const float* __restrict__ scale,
                                              const float* __restrict__ bias,
                                              float* __restrict__ out) {
  __shared__ f16 sA[128 * 64];
  __shared__ f16 sB[128 * 64];
  int tid = threadIdx.x;
  int wid = tid >> 6, lane = tid & 63;
  int wm = wid >> 1, wn = wid & 1;
  int ln = lane & 15, q = lane >> 4;
  int bid = blockIdx.x;
  int swz = (bid & 7) * 256 + (bid >> 3);   // XCD-aware, bijective (2048 % 8 == 0)
  int bm = swz >> 5, bn = swz & 31;         // 8 row-panels x all cols per XCD
  size_t brow = (size_t)bm * 128;
  int bcol = bn * 128;
  f32x4 acc[4][4] = {};
  for (int kt = 0; kt < 4096; kt += 64) {
    __syncthreads();
    stage_tile(xh, brow, kt, 4096, sA, wid, lane);
    stage_tile(ch, bcol, kt, 4096, sB, wid, lane);
    __syncthreads();
#pragma unroll
    for (int ks = 0; ks < 2; ++ks) {
      f16x8 af[4], bf[4];
#pragma unroll
      for (int mi = 0; mi < 4; ++mi)
        af[mi] = *reinterpret_cast<const f16x8*>(&sA[(wm * 64 + mi * 16 + ln) * 64 + ks * 32 + q * 8]);
#pragma unroll
      for (int ni = 0; ni < 4; ++ni)
        bf[ni] = *reinterpret_cast<const f16x8*>(&sB[(wn * 64 + ni * 16 + ln) * 64 + ks * 32 + q * 8]);
#pragma unroll
      for (int mi = 0; mi < 4; ++mi)
#pragma unroll
        for (int ni = 0; ni < 4; ++ni)
          acc[mi][ni] = mfma16(af[mi], bf[ni], acc[mi][ni]);
    }
  }
#pragma unroll
  for (int ni = 0; ni < 4; ++ni) {
    int col = bcol + wn * 64 + ni * 16 + ln;
    float sc = scale[col], bs = bias[col];
#pragma unroll
    for (int mi = 0; mi < 4; ++mi)
#pragma unroll
      for (int j = 0; j < 4; ++j) {
        size_t row = brow + wm * 64 + mi * 16 + q * 4 + j;
        out[row * 4096 + col] = sc * acc[mi][ni][j] + bs;
      }
  }
}

extern "C" void kernel_launch(void* const* d_in, const int* in_sizes, int n_in,
                              void* d_out, int out_size, void* d_ws, size_t ws_size,
                              hipStream_t stream) {
  const float* x    = (const float*)d_in[0];
  const float* base = (const float*)d_in[1];
  const float* bias = (const float*)d_in[2];
  const float* lA   = (const float*)d_in[3];
  const float* lB   = (const float*)d_in[4];
  const float* mag  = (const float*)d_in[5];
  const float* turk = (const float*)d_in[6];
  float* out = (float*)d_out;
  char* ws = (char*)d_ws;

  f16*   xh      = (f16*)(ws);                        // 8192*4096*2  = 64 MiB
  f16*   ch      = (f16*)(ws + 67108864);             // 4096*4096*2  = 32 MiB
  f16*   at      = (f16*)(ws + 100663296);            // 4096*256*2   =  2 MiB
  f16*   bh      = (f16*)(ws + 102760448);            // 4096*256*2   =  2 MiB
  float* partial = (float*)(ws + 104857600);          // 4096*32*4    = 512 KiB
  float* scale   = (float*)(ws + 105381888);          // 4096*4       = 16 KiB

  k_cvt<<<16384, 256, 0, stream>>>(x, xh, 4194304);     // x -> f16
  k_cvt<<<512, 256, 0, stream>>>(lB, bh, 131072);       // lora_B -> f16
  k_cvt_at<<<dim3(64, 4), 256, 0, stream>>>(lA, at);    // lora_A -> f16 transposed
  k_lora<<<1024, 256, 0, stream>>>(bh, at, base, ch, partial);
  k_scale<<<16, 256, 0, stream>>>(partial, mag, turk, scale);
  k_main<<<2048, 256, 0, stream>>>(xh, ch, scale, bias, out);
}

// Round 2
// 406.357 us; speedup vs baseline: 1.2074x; 1.2074x over previous
//
#include <hip/hip_runtime.h>

typedef _Float16 f16;
typedef _Float16 f16x8 __attribute__((ext_vector_type(8)));
typedef float f32x4 __attribute__((ext_vector_type(4)));

__device__ __forceinline__ void gload_lds16(const void* g, void* l) {
  __builtin_amdgcn_global_load_lds((const __attribute__((address_space(1))) void*)g,
                                   (__attribute__((address_space(3))) void*)l, 16, 0, 0);
}

__device__ __forceinline__ f32x4 mfma16(f16x8 a, f16x8 b, f32x4 c) {
  return __builtin_amdgcn_mfma_f32_16x16x32_f16(a, b, c, 0, 0, 0);
}

// ---------------- small prep kernels (unchanged from r1) ----------------

__global__ void k_cvt(const float* __restrict__ src, f16* __restrict__ dst, int n8) {
  int i = blockIdx.x * 256 + threadIdx.x;
  if (i >= n8) return;
  const float4* s4 = reinterpret_cast<const float4*>(src) + (size_t)i * 2;
  float4 a = s4[0], b = s4[1];
  f16x8 v;
  v[0] = (f16)a.x; v[1] = (f16)a.y; v[2] = (f16)a.z; v[3] = (f16)a.w;
  v[4] = (f16)b.x; v[5] = (f16)b.y; v[6] = (f16)b.z; v[7] = (f16)b.w;
  *reinterpret_cast<f16x8*>(dst + (size_t)i * 8) = v;
}

__global__ void k_cvt_at(const float* __restrict__ A, f16* __restrict__ at) {
  __shared__ float t[64][65];
  int bi = blockIdx.x, br = blockIdx.y;
  int tx = threadIdx.x & 63, ty = threadIdx.x >> 6;
#pragma unroll
  for (int p = 0; p < 16; ++p) {
    int r = p * 4 + ty;
    t[r][tx] = A[(size_t)(br * 64 + r) * 4096 + bi * 64 + tx];
  }
  __syncthreads();
#pragma unroll
  for (int p = 0; p < 16; ++p) {
    int i = p * 4 + ty;
    at[(size_t)(bi * 64 + i) * 256 + br * 64 + tx] = (f16)t[tx][i];
  }
}

// linear (unswizzled) 128x64 stage for k_lora
__device__ __forceinline__ void stage_tile_lin(const f16* __restrict__ g, size_t row0, int k0,
                                               int ldg, f16* s, int wid, int lane) {
#pragma unroll
  for (int t = 0; t < 4; ++t) {
    int c = (wid * 4 + t) * 64 + lane;
    const f16* gp = g + (row0 + (size_t)(c >> 3)) * (size_t)ldg + k0 + (c & 7) * 8;
    gload_lds16(gp, s + (wid * 4 + t) * 512);
  }
}

__global__ __launch_bounds__(256) void k_lora(const f16* __restrict__ bh,
                                              const f16* __restrict__ at,
                                              const float* __restrict__ base,
                                              f16* __restrict__ ch,
                                              float* __restrict__ partial) {
  __shared__ f16 sA[128 * 64];
  __shared__ f16 sB[128 * 64];
  __shared__ float ssum[2][128];
  int tid = threadIdx.x;
  int wid = tid >> 6, lane = tid & 63;
  int wm = wid >> 1, wn = wid & 1;
  int ln = lane & 15, q = lane >> 4;
  int bm = blockIdx.x >> 5, bn = blockIdx.x & 31;
  int brow = bm * 128, bcol = bn * 128;
  f32x4 acc[4][4] = {};
  for (int kt = 0; kt < 256; kt += 64) {
    __syncthreads();
    stage_tile_lin(bh, brow, kt, 256, sA, wid, lane);
    stage_tile_lin(at, bcol, kt, 256, sB, wid, lane);
    __syncthreads();
#pragma unroll
    for (int ks = 0; ks < 2; ++ks) {
      f16x8 af[4], bf[4];
#pragma unroll
      for (int mi = 0; mi < 4; ++mi)
        af[mi] = *reinterpret_cast<const f16x8*>(&sA[(wm * 64 + mi * 16 + ln) * 64 + ks * 32 + q * 8]);
#pragma unroll
      for (int ni = 0; ni < 4; ++ni)
        bf[ni] = *reinterpret_cast<const f16x8*>(&sB[(wn * 64 + ni * 16 + ln) * 64 + ks * 32 + q * 8]);
#pragma unroll
      for (int mi = 0; mi < 4; ++mi)
#pragma unroll
        for (int ni = 0; ni < 4; ++ni)
          acc[mi][ni] = mfma16(af[mi], bf[ni], acc[mi][ni]);
    }
  }
#pragma unroll
  for (int mi = 0; mi < 4; ++mi) {
#pragma unroll
    for (int j = 0; j < 4; ++j) {
      int row = brow + wm * 64 + mi * 16 + q * 4 + j;
      float s = 0.f;
#pragma unroll
      for (int ni = 0; ni < 4; ++ni) {
        int col = bcol + wn * 64 + ni * 16 + ln;
        float v = base[(size_t)row * 4096 + col] + 0.5f * acc[mi][ni][j];
        ch[(size_t)row * 4096 + col] = (f16)v;
        s += v * v;
      }
#pragma unroll
      for (int m = 1; m < 16; m <<= 1) s += __shfl_xor(s, m, 64);
      if (ln == 0) ssum[wn][wm * 64 + mi * 16 + q * 4 + j] = s;
    }
  }
  __syncthreads();
  if (tid < 128) {
    float p = ssum[0][tid] + ssum[1][tid];
    partial[(size_t)(brow + tid) * 32 + bn] = p;
  }
}

__global__ void k_scale(const float* __restrict__ partial, const float* __restrict__ mag,
                        const float* __restrict__ turk, float* __restrict__ scale) {
  int o = blockIdx.x * 256 + threadIdx.x;
  float s = 0.f;
#pragma unroll
  for (int c = 0; c < 32; ++c) s += partial[(size_t)o * 32 + c];
  scale[o] = mag[o] * turk[o] / (sqrtf(s) + 1e-8f);
}

// ---------------- 256x256 8-phase main GEMM ----------------
// LDS half-tile = [128 rows][8 slots of 8 f16]; slot stored XOR-swizzled:
// linear (row, slot) holds global[row][ (slot ^ (row&7))*8 .. +7 ].

// stage one half-tile (128 rows x 64 f16) : 2 x global_load_lds_dwordx4 per thread
__device__ __forceinline__ void stage_half(const f16* __restrict__ g, size_t grow0, int gk0,
                                           f16* lbase, int wid, int lane) {
#pragma unroll
  for (int l = 0; l < 2; ++l) {
    int c = (wid * 2 + l) * 64 + lane;         // 0..1023
    int row = c >> 3, slot = c & 7;
    const f16* gp = g + (grow0 + row) * (size_t)4096 + gk0 + ((slot ^ (row & 7)) * 8);
    gload_lds16(gp, lbase + (wid * 2 + l) * 512);
  }
}

__device__ __forceinline__ void load_a(const f16* half, int qm, int ln, int sw0, int sw1,
                                       f16x8 (&af)[2][2]) {
#pragma unroll
  for (int m = 0; m < 2; ++m) {
    const f16* rp = half + (qm * 32 + m * 16 + ln) * 64;
    af[m][0] = *reinterpret_cast<const f16x8*>(rp + sw0);
    af[m][1] = *reinterpret_cast<const f16x8*>(rp + sw1);
  }
}

__device__ __forceinline__ void load_b(const f16* half, int qn, int ln, int sw0, int sw1,
                                       f16x8 (&bf)[4][2]) {
#pragma unroll
  for (int n = 0; n < 4; ++n) {
    const f16* rp = half + (qn * 64 + n * 16 + ln) * 64;
    bf[n][0] = *reinterpret_cast<const f16x8*>(rp + sw0);
    bf[n][1] = *reinterpret_cast<const f16x8*>(rp + sw1);
  }
}

__device__ __forceinline__ void mfma_q(f16x8 (&af)[2][2], f16x8 (&bf)[4][2], f32x4 (&a)[2][4]) {
#pragma unroll
  for (int m = 0; m < 2; ++m)
#pragma unroll
    for (int n = 0; n < 4; ++n) {
      a[m][n] = mfma16(af[m][0], bf[n][0], a[m][n]);
      a[m][n] = mfma16(af[m][1], bf[n][1], a[m][n]);
    }
}

__global__ __launch_bounds__(512, 2) void k_main(const f16* __restrict__ xh,
                                                 const f16* __restrict__ ch,
                                                 const float* __restrict__ scale,
                                                 const float* __restrict__ bias,
                                                 float* __restrict__ out) {
  __shared__ __align__(16) f16 sA[32768];   // 2 bufs x 2 halves x 128x64
  __shared__ __align__(16) f16 sB[32768];
  int tid = threadIdx.x;
  int wid = tid >> 6, lane = tid & 63;
  int qm = wid >> 1, qn = wid & 1;          // 4x2 waves within a 128x128 quadrant
  int ln = lane & 15, q8 = lane >> 4;
  int sw0 = ((q8) ^ (ln & 7)) * 8;          // kstep 0 swizzled slot (f16 offset)
  int sw1 = ((4 + q8) ^ (ln & 7)) * 8;      // kstep 1

  int bid = blockIdx.x;                     // 512 blocks, 512 % 8 == 0
  int swz = (bid & 7) * 64 + (bid >> 3);    // XCD-aware, bijective
  int bm = swz >> 4, bn = swz & 15;
  size_t brow = (size_t)bm * 256;
  int bcol = bn * 256;

  f32x4 acc[4][2][4] = {};
  f16x8 af[2][2], bf[4][2];

  // prologue: t0 {A0,B1,A1,B0} -> buf0 ; t1 {A0,B1} -> buf1
  stage_half(xh, brow + 0,           0, sA + 0,             wid, lane);
  stage_half(ch, (size_t)bcol + 128, 0, sB + 8192,          wid, lane);
  stage_half(xh, brow + 128,         0, sA + 8192,          wid, lane);
  stage_half(ch, (size_t)bcol + 0,   0, sB + 0,             wid, lane);
  stage_half(xh, brow + 0,          64, sA + 16384,         wid, lane);
  stage_half(ch, (size_t)bcol + 128,64, sB + 16384 + 8192,  wid, lane);
  asm volatile("s_waitcnt vmcnt(4)");
  __builtin_amdgcn_s_barrier();
  __builtin_amdgcn_sched_barrier(0);

#define KTILE(CUR, T)                                                                     \
  {                                                                                       \
    const int NC = (CUR) ^ 1;                                                             \
    f16* cA = sA + (CUR) * 16384;                                                         \
    f16* cB = sB + (CUR) * 16384;                                                         \
    int t1 = (T) + 1; if (t1 > 63) t1 = 63;                                               \
    int t2 = (T) + 2; if (t2 > 63) t2 = 63;                                               \
    /* ph1: q0=(A0,B0); stage (T+1):A1 -> buf[NC].A1 */                                   \
    load_a(cA, qm, ln, sw0, sw1, af);                                                     \
    load_b(cB, qn, ln, sw0, sw1, bf);                                                     \
    stage_half(xh, brow + 128, t1 * 64, sA + NC * 16384 + 8192, wid, lane);               \
    asm volatile("s_waitcnt lgkmcnt(8)");                                                 \
    __builtin_amdgcn_s_barrier();                                                         \
    asm volatile("s_waitcnt lgkmcnt(0)");                                                 \
    __builtin_amdgcn_sched_barrier(0);                                                    \
    __builtin_amdgcn_s_setprio(1); mfma_q(af, bf, acc[0]); __builtin_amdgcn_s_setprio(0); \
    __builtin_amdgcn_s_barrier();                                                         \
    __builtin_amdgcn_sched_barrier(0);                                                    \
    /* ph2: q1=(A0,B1); stage (T+1):B0 -> buf[NC].B0 */                                   \
    load_b(cB + 8192, qn, ln, sw0, sw1, bf);                                              \
    stage_half(ch, (size_t)bcol + 0, t1 * 64, sB + NC * 16384, wid, lane);                \
    __builtin_amdgcn_s_barrier();                                                         \
    asm volatile("s_waitcnt lgkmcnt(0)");                                                 \
    __builtin_amdgcn_sched_barrier(0);                                                    \
    __builtin_amdgcn_s_setprio(1); mfma_q(af, bf, acc[1]); __builtin_amdgcn_s_setprio(0); \
    __builtin_amdgcn_s_barrier();                                                         \
    __builtin_amdgcn_sched_barrier(0);                                                    \
    /* ph3: q2=(A1,B1); stage (T+2):A0 -> buf[CUR].A0 */                                  \
    load_a(cA + 8192, qm, ln, sw0, sw1, af);                                              \
    stage_half(xh, brow + 0, t2 * 64, sA + (CUR) * 16384, wid, lane);                     \
    __builtin_amdgcn_s_barrier();                                                         \
    asm volatile("s_waitcnt lgkmcnt(0)");                                                 \
    __builtin_amdgcn_sched_barrier(0);                                                    \
    __builtin_amdgcn_s_setprio(1); mfma_q(af, bf, acc[2]); __builtin_amdgcn_s_setprio(0); \
    __builtin_amdgcn_s_barrier();                                                         \
    __builtin_amdgcn_sched_barrier(0);                                                    \
    /* ph4: q3=(A1,B0); stage (T+2):B1 -> buf[CUR].B1 */                                  \
    load_b(cB, qn, ln, sw0, sw1, bf);                                                     \
    stage_half(ch, (size_t)bcol + 128, t2 * 64, sB + (CUR) * 16384 + 8192, wid, lane);    \
    asm volatile("s_waitcnt vmcnt(4)");                                                   \
    __builtin_amdgcn_s_barrier();                                                         \
    asm volatile("s_waitcnt lgkmcnt(0)");                                                 \
    __builtin_amdgcn_sched_barrier(0);                                                    \
    __builtin_amdgcn_s_setprio(1); mfma_q(af, bf, acc[3]); __builtin_amdgcn_s_setprio(0); \
    __builtin_amdgcn_s_barrier();                                                         \
    __builtin_amdgcn_sched_barrier(0);                                                    \
  }

  for (int t = 0; t < 64; t += 2) {
    KTILE(0, t)
    KTILE(1, t + 1)
  }
#undef KTILE

  asm volatile("s_waitcnt vmcnt(0)");

  // epilogue: quadrant q -> (QA, QB); out = scale[col]*acc + bias[col]
  const int QA[4] = {0, 0, 1, 1};
  const int QB[4] = {0, 1, 1, 0};
#pragma unroll
  for (int q = 0; q < 4; ++q)
#pragma unroll
    for (int n = 0; n < 4; ++n) {
      int col = bcol + QB[q] * 128 + qn * 64 + n * 16 + ln;
      float sc = scale[col], bs = bias[col];
#pragma unroll
      for (int m = 0; m < 2; ++m)
#pragma unroll
        for (int j = 0; j < 4; ++j) {
          size_t row = brow + QA[q] * 128 + qm * 32 + m * 16 + q8 * 4 + j;
          out[row * 4096 + col] = sc * acc[q][m][n][j] + bs;
        }
    }
}

extern "C" void kernel_launch(void* const* d_in, const int* in_sizes, int n_in,
                              void* d_out, int out_size, void* d_ws, size_t ws_size,
                              hipStream_t stream) {
  const float* x    = (const float*)d_in[0];
  const float* base = (const float*)d_in[1];
  const float* bias = (const float*)d_in[2];
  const float* lA   = (const float*)d_in[3];
  const float* lB   = (const float*)d_in[4];
  const float* mag  = (const float*)d_in[5];
  const float* turk = (const float*)d_in[6];
  float* out = (float*)d_out;
  char* ws = (char*)d_ws;

  f16*   xh      = (f16*)(ws);                        // 64 MiB
  f16*   ch      = (f16*)(ws + 67108864);             // 32 MiB
  f16*   at      = (f16*)(ws + 100663296);            //  2 MiB
  f16*   bh      = (f16*)(ws + 102760448);            //  2 MiB
  float* partial = (float*)(ws + 104857600);          // 512 KiB
  float* scale   = (float*)(ws + 105381888);          // 16 KiB

  k_cvt<<<16384, 256, 0, stream>>>(x, xh, 4194304);
  k_cvt<<<512, 256, 0, stream>>>(lB, bh, 131072);
  k_cvt_at<<<dim3(64, 4), 256, 0, stream>>>(lA, at);
  k_lora<<<1024, 256, 0, stream>>>(bh, at, base, ch, partial);
  k_scale<<<16, 256, 0, stream>>>(partial, mag, turk, scale);
  k_main<<<512, 512, 0, stream>>>(xh, ch, scale, bias, out);
}

// Round 3
// 357.292 us; speedup vs baseline: 1.3732x; 1.1373x over previous
//
#include <hip/hip_runtime.h>

typedef _Float16 f16;
typedef _Float16 f16x8 __attribute__((ext_vector_type(8)));
typedef float f32x4 __attribute__((ext_vector_type(4)));

__device__ __forceinline__ void gload_lds16(const void* g, void* l) {
  __builtin_amdgcn_global_load_lds((const __attribute__((address_space(1))) void*)g,
                                   (__attribute__((address_space(3))) void*)l, 16, 0, 0);
}

__device__ __forceinline__ f32x4 mfma16(f16x8 a, f16x8 b, f32x4 c) {
  return __builtin_amdgcn_mfma_f32_16x16x32_f16(a, b, c, 0, 0, 0);
}

// ---------------- small prep kernels (unchanged) ----------------

__global__ void k_cvt(const float* __restrict__ src, f16* __restrict__ dst, int n8) {
  int i = blockIdx.x * 256 + threadIdx.x;
  if (i >= n8) return;
  const float4* s4 = reinterpret_cast<const float4*>(src) + (size_t)i * 2;
  float4 a = s4[0], b = s4[1];
  f16x8 v;
  v[0] = (f16)a.x; v[1] = (f16)a.y; v[2] = (f16)a.z; v[3] = (f16)a.w;
  v[4] = (f16)b.x; v[5] = (f16)b.y; v[6] = (f16)b.z; v[7] = (f16)b.w;
  *reinterpret_cast<f16x8*>(dst + (size_t)i * 8) = v;
}

__global__ void k_cvt_at(const float* __restrict__ A, f16* __restrict__ at) {
  __shared__ float t[64][65];
  int bi = blockIdx.x, br = blockIdx.y;
  int tx = threadIdx.x & 63, ty = threadIdx.x >> 6;
#pragma unroll
  for (int p = 0; p < 16; ++p) {
    int r = p * 4 + ty;
    t[r][tx] = A[(size_t)(br * 64 + r) * 4096 + bi * 64 + tx];
  }
  __syncthreads();
#pragma unroll
  for (int p = 0; p < 16; ++p) {
    int i = p * 4 + ty;
    at[(size_t)(bi * 64 + i) * 256 + br * 64 + tx] = (f16)t[tx][i];
  }
}

__device__ __forceinline__ void stage_tile_lin(const f16* __restrict__ g, size_t row0, int k0,
                                               int ldg, f16* s, int wid, int lane) {
#pragma unroll
  for (int t = 0; t < 4; ++t) {
    int c = (wid * 4 + t) * 64 + lane;
    const f16* gp = g + (row0 + (size_t)(c >> 3)) * (size_t)ldg + k0 + (c & 7) * 8;
    gload_lds16(gp, s + (wid * 4 + t) * 512);
  }
}

__global__ __launch_bounds__(256) void k_lora(const f16* __restrict__ bh,
                                              const f16* __restrict__ at,
                                              const float* __restrict__ base,
                                              f16* __restrict__ ch,
                                              float* __restrict__ partial) {
  __shared__ f16 sA[128 * 64];
  __shared__ f16 sB[128 * 64];
  __shared__ float ssum[2][128];
  int tid = threadIdx.x;
  int wid = tid >> 6, lane = tid & 63;
  int wm = wid >> 1, wn = wid & 1;
  int ln = lane & 15, q = lane >> 4;
  int bm = blockIdx.x >> 5, bn = blockIdx.x & 31;
  int brow = bm * 128, bcol = bn * 128;
  f32x4 acc[4][4] = {};
  for (int kt = 0; kt < 256; kt += 64) {
    __syncthreads();
    stage_tile_lin(bh, brow, kt, 256, sA, wid, lane);
    stage_tile_lin(at, bcol, kt, 256, sB, wid, lane);
    __syncthreads();
#pragma unroll
    for (int ks = 0; ks < 2; ++ks) {
      f16x8 af[4], bf[4];
#pragma unroll
      for (int mi = 0; mi < 4; ++mi)
        af[mi] = *reinterpret_cast<const f16x8*>(&sA[(wm * 64 + mi * 16 + ln) * 64 + ks * 32 + q * 8]);
#pragma unroll
      for (int ni = 0; ni < 4; ++ni)
        bf[ni] = *reinterpret_cast<const f16x8*>(&sB[(wn * 64 + ni * 16 + ln) * 64 + ks * 32 + q * 8]);
#pragma unroll
      for (int mi = 0; mi < 4; ++mi)
#pragma unroll
        for (int ni = 0; ni < 4; ++ni)
          acc[mi][ni] = mfma16(af[mi], bf[ni], acc[mi][ni]);
    }
  }
#pragma unroll
  for (int mi = 0; mi < 4; ++mi) {
#pragma unroll
    for (int j = 0; j < 4; ++j) {
      int row = brow + wm * 64 + mi * 16 + q * 4 + j;
      float s = 0.f;
#pragma unroll
      for (int ni = 0; ni < 4; ++ni) {
        int col = bcol + wn * 64 + ni * 16 + ln;
        float v = base[(size_t)row * 4096 + col] + 0.5f * acc[mi][ni][j];
        ch[(size_t)row * 4096 + col] = (f16)v;
        s += v * v;
      }
#pragma unroll
      for (int m = 1; m < 16; m <<= 1) s += __shfl_xor(s, m, 64);
      if (ln == 0) ssum[wn][wm * 64 + mi * 16 + q * 4 + j] = s;
    }
  }
  __syncthreads();
  if (tid < 128) {
    float p = ssum[0][tid] + ssum[1][tid];
    partial[(size_t)(brow + tid) * 32 + bn] = p;
  }
}

__global__ void k_scale(const float* __restrict__ partial, const float* __restrict__ mag,
                        const float* __restrict__ turk, float* __restrict__ scale) {
  int o = blockIdx.x * 256 + threadIdx.x;
  float s = 0.f;
#pragma unroll
  for (int c = 0; c < 32; ++c) s += partial[(size_t)o * 32 + c];
  scale[o] = mag[o] * turk[o] / (sqrtf(s) + 1e-8f);
}

// ---------------- 256x256 8-phase main GEMM, m201 geometry ----------------
// Waves: 2M x 4N. Per-wave output 128x64. acc[8][4]. 24 ds_read_b128/wave/tile.
// LDS half = [128 rows][8 slots of 8 f16], slot stored XOR (row&7).

__device__ __forceinline__ void stage_half(const f16* __restrict__ g, size_t grow0, int gk0,
                                           f16* lbase, int wid, int lane) {
#pragma unroll
  for (int l = 0; l < 2; ++l) {
    int c = (wid * 2 + l) * 64 + lane;         // 0..1023
    int row = c >> 3, slot = c & 7;
    const f16* gp = g + (grow0 + row) * (size_t)4096 + gk0 + ((slot ^ (row & 7)) * 8);
    gload_lds16(gp, lbase + (wid * 2 + l) * 512);
  }
}

__device__ __forceinline__ void lda4(const f16* base, int g, int ln, int sw, f16x8 (&af)[4]) {
#pragma unroll
  for (int f = 0; f < 4; ++f)
    af[f] = *reinterpret_cast<const f16x8*>(base + (g * 64 + f * 16 + ln) * 64 + sw);
}

__device__ __forceinline__ void ldb4(const f16* base, int ln, int sw, f16x8 (&bf)[4]) {
#pragma unroll
  for (int n = 0; n < 4; ++n)
    bf[n] = *reinterpret_cast<const f16x8*>(base + (n * 16 + ln) * 64 + sw);
}

template <int G>
__device__ __forceinline__ void mfma16x(f16x8 (&af)[4], f16x8 (&bf)[4], f32x4 (&acc)[8][4]) {
#pragma unroll
  for (int f = 0; f < 4; ++f)
#pragma unroll
    for (int n = 0; n < 4; ++n)
      acc[G * 4 + f][n] = mfma16(af[f], bf[n], acc[G * 4 + f][n]);
}

__global__ __launch_bounds__(512, 2) void k_main(const f16* __restrict__ xh,
                                                 const f16* __restrict__ ch,
                                                 const float* __restrict__ scale,
                                                 const float* __restrict__ bias,
                                                 float* __restrict__ out) {
  __shared__ __align__(16) f16 sA[32768];   // 2 bufs x 2 halves x 128x64
  __shared__ __align__(16) f16 sB[32768];
  int tid = threadIdx.x;
  int wid = tid >> 6, lane = tid & 63;
  int wm = wid >> 2, wn = wid & 3;          // 2M x 4N
  int ln = lane & 15, q8 = lane >> 4;
  int sw0 = (q8 ^ (ln & 7)) * 8;
  int sw1 = ((4 + q8) ^ (ln & 7)) * 8;

  int bid = blockIdx.x;
  int swz = (bid & 7) * 64 + (bid >> 3);    // XCD-aware, bijective (512 % 8 == 0)
  int bm = swz >> 4, bn = swz & 15;
  size_t brow = (size_t)bm * 256;
  int bcol = bn * 256;

  f32x4 acc[8][4] = {};
  f16x8 af0[4], af1[4], af2[4], af3[4], bf0[4], bf1[4];

  // per-wave read bases
  const int aOff = wm * 8192;                               // own A half
  const int bOff = (wn >> 1) * 8192 + (wn & 1) * 4096;      // own B half + quarter

  // prologue: t0 {Ah0,Ah1,Bh0,Bh1} -> buf0 ; t1 {Ah1,Ah0} -> buf1
  stage_half(xh, brow + 0,            0, sA + 0,            wid, lane);
  stage_half(xh, brow + 128,          0, sA + 8192,         wid, lane);
  stage_half(ch, (size_t)bcol + 0,    0, sB + 0,            wid, lane);
  stage_half(ch, (size_t)bcol + 128,  0, sB + 8192,         wid, lane);
  stage_half(xh, brow + 128,         64, sA + 16384 + 8192, wid, lane);
  stage_half(xh, brow + 0,           64, sA + 16384,        wid, lane);
  asm volatile("s_waitcnt vmcnt(4)");
  __builtin_amdgcn_s_barrier();

#define KTILE(CUR, T)                                                                      \
  {                                                                                        \
    const int NC = (CUR) ^ 1;                                                              \
    const f16* cA = sA + (CUR) * 16384 + aOff;                                             \
    const f16* cB = sB + (CUR) * 16384 + bOff;                                             \
    int t1 = (T) + 1; if (t1 > 63) t1 = 63;                                                \
    int t2 = (T) + 2; if (t2 > 63) t2 = 63;                                                \
    /* ph0: (g0,s0); stage t+1:Bh0 -> buf[NC] */                                           \
    lda4(cA, 0, ln, sw0, af0); ldb4(cB, ln, sw0, bf0);                                     \
    stage_half(ch, (size_t)bcol + 0, t1 * 64, sB + NC * 16384, wid, lane);                 \
    __builtin_amdgcn_s_barrier();                                                          \
    asm volatile("s_waitcnt lgkmcnt(0)");                                                  \
    __builtin_amdgcn_s_setprio(1); mfma16x<0>(af0, bf0, acc); __builtin_amdgcn_s_setprio(0); \
    __builtin_amdgcn_s_barrier();                                                          \
    /* ph1: (g0,s1); stage t+1:Bh1 -> buf[NC] */                                           \
    lda4(cA, 0, ln, sw1, af1); lda4(cA, 1, ln, sw0, af2); ldb4(cB, ln, sw1, bf1);          \
    stage_half(ch, (size_t)bcol + 128, t1 * 64, sB + NC * 16384 + 8192, wid, lane);        \
    asm volatile("s_waitcnt lgkmcnt(8)");                                                  \
    __builtin_amdgcn_s_barrier();                                                          \
    asm volatile("s_waitcnt lgkmcnt(0)");                                                  \
    __builtin_amdgcn_s_setprio(1); mfma16x<0>(af1, bf1, acc); __builtin_amdgcn_s_setprio(0); \
    __builtin_amdgcn_s_barrier();                                                          \
    /* ph2: (g1,s0); stage t+2:Ah1 -> buf[CUR] (A-h1 reads end this phase) */              \
    lda4(cA, 1, ln, sw1, af3);                                                             \
    stage_half(xh, brow + 128, t2 * 64, sA + (CUR) * 16384 + 8192, wid, lane);             \
    __builtin_amdgcn_s_barrier();                                                          \
    asm volatile("s_waitcnt lgkmcnt(0)");                                                  \
    __builtin_amdgcn_s_setprio(1); mfma16x<1>(af2, bf0, acc); __builtin_amdgcn_s_setprio(0); \
    __builtin_amdgcn_s_barrier();                                                          \
    /* ph3: (g1,s1); no ds_reads; stage t+2:Ah0 -> buf[CUR]; boundary vmcnt(4) */          \
    stage_half(xh, brow + 0, t2 * 64, sA + (CUR) * 16384, wid, lane);                      \
    __builtin_amdgcn_s_barrier();                                                          \
    __builtin_amdgcn_s_setprio(1); mfma16x<1>(af3, bf1, acc); __builtin_amdgcn_s_setprio(0); \
    asm volatile("s_waitcnt vmcnt(4)");                                                    \
    __builtin_amdgcn_s_barrier();                                                          \
  }

  for (int t = 0; t < 64; t += 2) {
    KTILE(0, t)
    KTILE(1, t + 1)
  }
#undef KTILE

  asm volatile("s_waitcnt vmcnt(0)");

  // epilogue: out = scale[col]*acc + bias[col]
#pragma unroll
  for (int n = 0; n < 4; ++n) {
    int col = bcol + wn * 64 + n * 16 + ln;
    float sc = scale[col], bs = bias[col];
#pragma unroll
    for (int mf = 0; mf < 8; ++mf)
#pragma unroll
      for (int j = 0; j < 4; ++j) {
        size_t row = brow + wm * 128 + mf * 16 + q8 * 4 + j;
        out[row * 4096 + col] = sc * acc[mf][n][j] + bs;
      }
  }
}

extern "C" void kernel_launch(void* const* d_in, const int* in_sizes, int n_in,
                              void* d_out, int out_size, void* d_ws, size_t ws_size,
                              hipStream_t stream) {
  const float* x    = (const float*)d_in[0];
  const float* base = (const float*)d_in[1];
  const float* bias = (const float*)d_in[2];
  const float* lA   = (const float*)d_in[3];
  const float* lB   = (const float*)d_in[4];
  const float* mag  = (const float*)d_in[5];
  const float* turk = (const float*)d_in[6];
  float* out = (float*)d_out;
  char* ws = (char*)d_ws;

  f16*   xh      = (f16*)(ws);                        // 64 MiB
  f16*   ch      = (f16*)(ws + 67108864);             // 32 MiB
  f16*   at      = (f16*)(ws + 100663296);            //  2 MiB
  f16*   bh      = (f16*)(ws + 102760448);            //  2 MiB
  float* partial = (float*)(ws + 104857600);          // 512 KiB
  float* scale   = (float*)(ws + 105381888);          // 16 KiB

  k_cvt<<<16384, 256, 0, stream>>>(x, xh, 4194304);
  k_cvt<<<512, 256, 0, stream>>>(lB, bh, 131072);
  k_cvt_at<<<dim3(64, 4), 256, 0, stream>>>(lA, at);
  k_lora<<<1024, 256, 0, stream>>>(bh, at, base, ch, partial);
  k_scale<<<16, 256, 0, stream>>>(partial, mag, turk, scale);
  k_main<<<512, 512, 0, stream>>>(xh, ch, scale, bias, out);
}